// Round 9
// baseline (470.782 us; speedup 1.0000x reference)
//
#include <hip/hip_runtime.h>
#include <hip/hip_fp16.h>
#include <hip/hip_fp8.h>

#define B_ 256
#define V_ 1000
#define P_ 200
#define L_ 50
#define H_ 384
#define H3_ 1152
#define NW_ 10
#define OUT1_OFF 12800000

typedef _Float16 half8 __attribute__((ext_vector_type(8)));
typedef _Float16 half4_t __attribute__((ext_vector_type(4)));
typedef float floatx4 __attribute__((ext_vector_type(4)));

// ---------------------------------------------------------------------------
// prep: fp8 pair-packed w_hh in TWO regions (persistent / streamed),
// 12-wave layout, f16 gi operands, gate softmax, out1.
// Common formula: fragment (w, kappa, tau, p, l, e):
//   g=tau>>1; j=tau&1; kc=2*kappa+p;
//   row = g*384 + 32w + 16j + (l&15); col = kc*32 + (l>>4)*8 + e
// Persistent (kappa 0..1): byte i = ((w*12 + kappa*6 + tau)*64 + l)*16 + p*8 + e
// Streamed  (kappa 2..5): byte i = ((w*24 + (kappa-2)*6 + tau)*64 + l)*16 + p*8 + e
// ---------------------------------------------------------------------------
__global__ __launch_bounds__(256) void prep_kernel(
    const float* __restrict__ gate_emb, const float* __restrict__ prog_emb,
    const float* __restrict__ w_ih, const float* __restrict__ w_hh,
    const int* __restrict__ instr, const int* __restrict__ tacts,
    float* __restrict__ g01, unsigned char* __restrict__ whhP,
    unsigned char* __restrict__ whhS,
    _Float16* __restrict__ wih_h, _Float16* __restrict__ prog_h,
    float* __restrict__ out)
{
  const int stride = gridDim.x * blockDim.x;
  const int tid = blockIdx.x * blockDim.x + threadIdx.x;

  for (int i = tid; i < 147456; i += stride) {
    const int e = i & 7, p = (i >> 3) & 1, l = (i >> 4) & 63;
    const int q = i >> 10;                 // [0,144)
    const int u = q % 12, w = q / 12;
    const int kappa = u / 6, tau = u - 6*kappa;
    const int g = tau >> 1, j = tau & 1;
    const int kc = 2*kappa + p;
    const int row = g*384 + 32*w + 16*j + (l & 15);
    const int col = kc*32 + (l >> 4)*8 + e;
    __hip_fp8_e4m3 qv(w_hh[row*H_ + col]);
    whhP[i] = qv.__x;
  }
  for (int i = tid; i < 294912; i += stride) {
    const int e = i & 7, p = (i >> 3) & 1, l = (i >> 4) & 63;
    const int q = i >> 10;                 // [0,288)
    const int s = q % 24, w = q / 24;
    const int kappa = 2 + s / 6, tau = s % 6;
    const int g = tau >> 1, j = tau & 1;
    const int kc = 2*kappa + p;
    const int row = g*384 + 32*w + 16*j + (l & 15);
    const int col = kc*32 + (l >> 4)*8 + e;
    __hip_fp8_e4m3 qv(w_hh[row*H_ + col]);
    whhS[i] = qv.__x;
  }
  for (int i = tid; i < H3_*224; i += stride) {
    int r = i / 224, c = i - r*224;
    wih_h[i] = (_Float16)(c < P_ ? w_ih[r*P_ + c] : 0.f);
  }
  for (int i = tid; i < V_*P_; i += stride) prog_h[i] = (_Float16)prog_emb[i];
  for (int i = tid; i < NW_*B_; i += stride) {
    int w = i / B_, b = i - w*B_;
    int word = instr[(1+w)*B_ + b];
    float e0 = gate_emb[word*2], e1 = gate_emb[word*2+1];
    float m = fmaxf(e0, e1);
    float a = __expf(e0-m), c = __expf(e1-m);
    float inv = 1.f/(a+c);
    g01[i*2] = a*inv; g01[i*2+1] = c*inv;
  }
  for (int i = tid; i < B_*L_; i += stride) {
    int b = i / L_, l = i - b*L_;
    out[OUT1_OFF + i] = (float)tacts[(1+l)*B_ + b];
  }
}

// ---------------------------------------------------------------------------
// gi_gemm: giv[v][n] = program_emb[v] @ w_ih.T + b_ih   (vocab-wide, once)
// ---------------------------------------------------------------------------
__global__ __launch_bounds__(256) void gi_gemm(
    const _Float16* __restrict__ prog_h, const _Float16* __restrict__ wih_h,
    const float* __restrict__ b_ih, float* __restrict__ giv)
{
  __shared__ _Float16 pA[16][232];
  const int tid = threadIdx.x;
  const int v0 = blockIdx.x * 16;
  const int n0 = blockIdx.y * 64;

  for (int i = tid; i < 16*224; i += 256) {
    int r = i / 224, c = i - r*224;
    int v = v0 + r;
    _Float16 val = (_Float16)0.f;
    if (v < V_ && c < P_) val = prog_h[v*P_ + c];
    pA[r][c] = val;
  }
  __syncthreads();

  const int wave = tid >> 6, lane = tid & 63;
  const int m = lane & 15, kg = lane >> 4;
  const int n_t = n0 + wave*16;
  floatx4 acc = {0.f, 0.f, 0.f, 0.f};
  #pragma unroll
  for (int ks = 0; ks < 7; ++ks) {
    const int kk = ks*32 + kg*8;
    half8 av = *(const half8*)&pA[m][kk];
    half8 bv = *(const half8*)&wih_h[(n_t + m)*224 + kk];
    acc = __builtin_amdgcn_mfma_f32_16x16x32_f16(av, bv, acc, 0, 0, 0);
  }
  const int nn = n_t + m;
  const float bias = b_ih[nn];
  #pragma unroll
  for (int r = 0; r < 4; ++r) {
    int mm = v0 + kg*4 + r;
    if (mm < V_) giv[(size_t)mm*H3_ + nn] = acc[r] + bias;
  }
}

// ---------------------------------------------------------------------------
// steps: GRU recurrence, 16 blocks x 768 threads (12 waves, 3/SIMD).
// kappa 0..1 weight fragments LDS-PERSISTENT (144 KB, loaded once).
// kappa 2..5 stream straight to 8 named registers (depth-8 rotation,
// 24 units/wave/step, all indices compile-time). A-fragments read per-kappa
// from the 6 KB fp8 h image. 2 raw lgkm barriers/step.
// ---------------------------------------------------------------------------
__global__ __launch_bounds__(768, 3) void steps_kernel(
    const uint4* __restrict__ whhPp, const uint4* __restrict__ whhSp,
    const float* __restrict__ giv, const float* __restrict__ g01,
    const float* __restrict__ keys, const float* __restrict__ bhh,
    const int* __restrict__ instr, _Float16* __restrict__ hdump)
{
  __shared__ uint4 ldsP[9216];             // 147456 B persistent weights
  __shared__ unsigned long long hA[768];   // 6144 B fp8 h image

  const int bid = blockIdx.x, b0 = bid*16, tid = threadIdx.x;
  const int w = tid >> 6, lane = tid & 63, m_ = lane & 15, kg = lane >> 4;

  const uint4* __restrict__ sbase = whhSp + (size_t)w*24*64 + lane;

  float hreg[2][4];            // [j][r]: col 32w+16j+m_, batch kg*4+r
  float bb[6];                 // [g*2+j]
  float gvv[4][6];             // [r][g*2+j]
  float g0r[4], g1r[4];
  int wdr[4];

  // persistent weights -> LDS (once)
  for (int i = tid; i < 9216; i += 768) ldsP[i] = whhPp[i];

  #pragma unroll
  for (int g = 0; g < 3; ++g)
    #pragma unroll
    for (int j = 0; j < 2; ++j)
      bb[g*2+j] = bhh[g*384 + 32*w + 16*j + m_];

  // h0 = tile(scratch_keys[0], 3)
  #pragma unroll
  for (int j = 0; j < 2; ++j) {
    const float h0 = keys[(32*w + 16*j + m_) & 127];
    #pragma unroll
    for (int r = 0; r < 4; ++r) hreg[j][r] = h0;
  }

  // initial fp8 hA image + h dump slot 0
  #pragma unroll
  for (int j = 0; j < 2; ++j) {
    const int c = 32*w + 16*j + m_;
    const int base = (c >> 5)*512 + ((c >> 3) & 3)*128 + (c & 7);
    half4_t hv;
    #pragma unroll
    for (int r = 0; r < 4; ++r) {
      __hip_fp8_e4m3 q(hreg[j][r]);
      ((unsigned char*)hA)[base + (kg*4 + r)*8] = q.__x;
      hv[r] = (_Float16)hreg[j][r];
    }
    *(half4_t*)&hdump[(((size_t)0*16 + bid)*384 + c)*16 + kg*4] = hv;
  }

  // word-0 parameter loads
  {
    int4 wd4 = *(const int4*)&instr[(1+0)*B_ + b0 + kg*4];
    wdr[0] = wd4.x; wdr[1] = wd4.y; wdr[2] = wd4.z; wdr[3] = wd4.w;
    #pragma unroll
    for (int r = 0; r < 4; ++r) {
      float2 gg = *(const float2*)&g01[(size_t)(b0 + kg*4 + r)*2];
      g0r[r] = gg.x; g1r[r] = gg.y;
    }
    #pragma unroll
    for (int r = 0; r < 4; ++r) {
      const float* gp = giv + (size_t)wdr[r]*H3_;
      #pragma unroll
      for (int g = 0; g < 3; ++g)
        #pragma unroll
        for (int j = 0; j < 2; ++j)
          gvv[r][g*2+j] = gp[g*384 + 32*w + 16*j + m_];
    }
  }

  // stream prologue: units 0..7
  uint4 r0 = sbase[0*64], r1 = sbase[1*64], r2 = sbase[2*64], r3 = sbase[3*64];
  uint4 r4 = sbase[4*64], r5 = sbase[5*64], r6 = sbase[6*64], r7 = sbase[7*64];

  asm volatile("s_waitcnt lgkmcnt(0)\n\ts_barrier" ::: "memory");  // hA+ldsP ready

#define LO64(W) ((long)((((unsigned long long)(W).y) << 32) | (W).x))
#define HI64(W) ((long)((((unsigned long long)(W).w) << 32) | (W).z))
#define SUNIT(W, T, SN) \
  acc[T] = __builtin_amdgcn_mfma_f32_16x16x32_fp8_fp8((long)a0, LO64(W), acc[T], 0, 0, 0); \
  acc[T] = __builtin_amdgcn_mfma_f32_16x16x32_fp8_fp8((long)a1, HI64(W), acc[T], 0, 0, 0); \
  W = sbase[(SN)*64];
#define PUNIT(KP, T) { \
  uint4 Wp = ldsP[(w*12 + (KP)*6 + (T))*64 + lane]; \
  acc[T] = __builtin_amdgcn_mfma_f32_16x16x32_fp8_fp8((long)a0, LO64(Wp), acc[T], 0, 0, 0); \
  acc[T] = __builtin_amdgcn_mfma_f32_16x16x32_fp8_fp8((long)a1, HI64(Wp), acc[T], 0, 0, 0); }

  #pragma unroll 1
  for (int t = 0; t < 30; ++t) {
    floatx4 acc[6];
    #pragma unroll
    for (int c = 0; c < 6; ++c) acc[c] = (floatx4){0.f, 0.f, 0.f, 0.f};

    unsigned long long a0, a1;
    // kappa = 0 (persistent)
    a0 = hA[0*64 + lane]; a1 = hA[1*64 + lane];
    PUNIT(0,0) PUNIT(0,1) PUNIT(0,2) PUNIT(0,3) PUNIT(0,4) PUNIT(0,5)
    // kappa = 1 (persistent)
    a0 = hA[2*64 + lane]; a1 = hA[3*64 + lane];
    PUNIT(1,0) PUNIT(1,1) PUNIT(1,2) PUNIT(1,3) PUNIT(1,4) PUNIT(1,5)
    // kappa = 2 (stream s=0..5)
    a0 = hA[4*64 + lane]; a1 = hA[5*64 + lane];
    SUNIT(r0,0,8)  SUNIT(r1,1,9)  SUNIT(r2,2,10) SUNIT(r3,3,11) SUNIT(r4,4,12) SUNIT(r5,5,13)
    // kappa = 3 (stream s=6..11)
    a0 = hA[6*64 + lane]; a1 = hA[7*64 + lane];
    SUNIT(r6,0,14) SUNIT(r7,1,15) SUNIT(r0,2,16) SUNIT(r1,3,17) SUNIT(r2,4,18) SUNIT(r3,5,19)
    // kappa = 4 (stream s=12..17; s>=16 loads next step's units 0,1)
    a0 = hA[8*64 + lane]; a1 = hA[9*64 + lane];
    SUNIT(r4,0,20) SUNIT(r5,1,21) SUNIT(r6,2,22) SUNIT(r7,3,23) SUNIT(r0,4,0)  SUNIT(r1,5,1)
    // kappa = 5 (stream s=18..23; loads next step's units 2..7)
    a0 = hA[10*64 + lane]; a1 = hA[11*64 + lane];
    SUNIT(r2,0,2)  SUNIT(r3,1,3)  SUNIT(r4,2,4)  SUNIT(r5,3,5)  SUNIT(r6,4,6)  SUNIT(r7,5,7)

    asm volatile("s_waitcnt lgkmcnt(0)\n\ts_barrier" ::: "memory"); // hA reads done

    // ---- fused GRU epilogue (wave-local) ----
    #pragma unroll
    for (int j = 0; j < 2; ++j) {
      #pragma unroll
      for (int r = 0; r < 4; ++r) {
        const float ghr = acc[0+j][r] + bb[0+j];
        const float ghz = acc[2+j][r] + bb[2+j];
        const float ghn = acc[4+j][r] + bb[4+j];
        const float rg = 1.f/(1.f + __expf(-(gvv[r][0+j] + ghr)));
        const float z  = 1.f/(1.f + __expf(-(gvv[r][2+j] + ghz)));
        const float x2 = gvv[r][4+j] + rg*ghn;
        const float nn = 2.f/(1.f + __expf(-2.f*x2)) - 1.f;   // tanh
        const float hold = hreg[j][r];
        const float hnew = (1.f - z)*nn + z*hold;
        hreg[j][r] = g0r[r]*hold + g1r[r]*hnew;
      }
    }

    // ---- new fp8 hA image + h dump slot t+1 ----
    #pragma unroll
    for (int j = 0; j < 2; ++j) {
      const int c = 32*w + 16*j + m_;
      const int base = (c >> 5)*512 + ((c >> 3) & 3)*128 + (c & 7);
      half4_t hv;
      #pragma unroll
      for (int r = 0; r < 4; ++r) {
        __hip_fp8_e4m3 q(hreg[j][r]);
        ((unsigned char*)hA)[base + (kg*4 + r)*8] = q.__x;
        hv[r] = (_Float16)hreg[j][r];
      }
      *(half4_t*)&hdump[(((size_t)(t+1)*16 + bid)*384 + c)*16 + kg*4] = hv;
    }

    // ---- word-boundary loads for next word ----
    if (t % 3 == 2) {
      const int wi = (t/3 + 1 < 10) ? t/3 + 1 : 9;
      int4 wd4 = *(const int4*)&instr[(1+wi)*B_ + b0 + kg*4];
      wdr[0] = wd4.x; wdr[1] = wd4.y; wdr[2] = wd4.z; wdr[3] = wd4.w;
      #pragma unroll
      for (int r = 0; r < 4; ++r) {
        float2 gg = *(const float2*)&g01[((size_t)wi*B_ + b0 + kg*4 + r)*2];
        g0r[r] = gg.x; g1r[r] = gg.y;
      }
      #pragma unroll
      for (int r = 0; r < 4; ++r) {
        const float* gp = giv + (size_t)wdr[r]*H3_;
        #pragma unroll
        for (int g = 0; g < 3; ++g)
          #pragma unroll
          for (int j = 0; j < 2; ++j)
            gvv[r][g*2+j] = gp[g*384 + 32*w + 16*j + m_];
      }
    }

    asm volatile("s_waitcnt lgkmcnt(0)\n\ts_barrier" ::: "memory"); // hA writes
  }
  asm volatile("s_waitcnt vmcnt(0) lgkmcnt(0)" ::: "memory");
#undef SUNIT
#undef PUNIT
#undef LO64
#undef HI64
}

// ---------------------------------------------------------------------------
// attnS: decoupled attention/S recurrence, one block per batch element.
// Phase 1: all 60 score rows in parallel; phase 2: 30-step S recurrence.
// ---------------------------------------------------------------------------
__global__ __launch_bounds__(256) void attnS_kernel(
    const _Float16* __restrict__ hdump, const float* __restrict__ keys,
    const float* __restrict__ g01, float* __restrict__ S_buf)
{
  __shared__ float keysT[128][52];   // [k][l]
  __shared__ float hT[30][256];      // h cols 128..383 per step
  __shared__ float sc[30][2][52];    // softmax probs
  __shared__ float Sr[50][13];
  __shared__ float g0a[10], g1a[10];
  __shared__ float nvs[12];

  const int b = blockIdx.x, g = b >> 4, bl = b & 15;
  const int tid = threadIdx.x, wv = tid >> 6, lane = tid & 63;

  for (int i = tid; i < 128*L_; i += 256) {
    int k = i / L_, l = i - k*L_;
    keysT[k][l] = keys[l*128 + k];
  }
  for (int i = tid; i < 30*256; i += 256) {
    int t = i >> 8, c = i & 255;
    hT[t][c] = (float)hdump[(((size_t)t*16 + g)*384 + 128 + c)*16 + bl];
  }
  for (int i = tid; i < 550; i += 256) Sr[i/11][i%11] = ((i % 11) == 0) ? 1.f : 0.f;
  if (tid < NW_) {
    float2 gg = *(const float2*)&g01[((size_t)tid*B_ + b)*2];
    g0a[tid] = gg.x; g1a[tid] = gg.y;
  }
  __syncthreads();

  // ---- phase 1: 60 score rows, 15 per wave ----
  for (int row = wv; row < 60; row += 4) {
    const int t = row >> 1, ty = row & 1;
    float s = 0.f;
    if (lane < L_) {
      #pragma unroll 8
      for (int k = 0; k < 128; ++k)
        s += hT[t][ty*128 + k] * keysT[k][lane];
    }
    float val = (lane < L_) ? s : -1e30f;
    float mx = val;
    #pragma unroll
    for (int off = 32; off; off >>= 1) mx = fmaxf(mx, __shfl_xor(mx, off));
    float e = (lane < L_) ? __expf(val - mx) : 0.f;
    float sm = e;
    #pragma unroll
    for (int off = 32; off; off >>= 1) sm += __shfl_xor(sm, off);
    if (lane < L_) sc[t][ty][lane] = e / sm;
  }
  __syncthreads();

  // ---- phase 2: S recurrence ----
  for (int t = 0; t < 30; ++t) {
    const int widx = t / 3;
    if (tid < 11) {
      float rv = 0.f;
      #pragma unroll 5
      for (int l = 0; l < L_; ++l) rv += sc[t][0][l] * Sr[l][tid];
      nvs[tid] = g1a[widx]*rv + ((tid == 1 + widx) ? g0a[widx] : 0.f);
    }
    __syncthreads();
    for (int i = tid; i < 550; i += 256) {
      const int l = i / 11, j = i - l*11;
      const float wm = sc[t][1][l];
      Sr[l][j] = wm*nvs[j] + (1.f - wm)*Sr[l][j];
    }
    __syncthreads();
  }

  for (int i = tid; i < 550; i += 256) {
    const int l = i / 11, j = i - l*11;
    S_buf[(size_t)b*600 + l*12 + j] = Sr[l][j];
  }
}

// ---------------------------------------------------------------------------
// write (lse fused): per (v-chunk of 125, b) block; contiguous stores.
// ---------------------------------------------------------------------------
__global__ __launch_bounds__(256) void write_kernel(
    const float* __restrict__ S_buf, const float* __restrict__ prim_emb,
    const float* __restrict__ iv_g, const int* __restrict__ instr,
    float* __restrict__ out)
{
  __shared__ float prim[10][1000];
  __shared__ float iv[1000];
  __shared__ float SrT[11][52];
  __shared__ float lss[52];
  __shared__ int wds[10];

  const int cx = blockIdx.x;      // 0..7
  const int b  = blockIdx.y;      // 0..255
  const int v0 = cx * 125;
  const int tid = threadIdx.x;

  if (tid < 10) wds[tid] = instr[(1+tid)*B_ + b];
  for (int i = tid; i < 550; i += 256) {
    int l = i / 11, j = i - l*11;
    SrT[j][l] = S_buf[(size_t)b*600 + l*12 + j];
  }
  for (int i = tid; i < 250; i += 256) ((float4*)iv)[i] = ((const float4*)iv_g)[i];
  __syncthreads();
  for (int wi = 0; wi < 10; ++wi) {
    const float4* __restrict__ src = (const float4*)(prim_emb + (size_t)wds[wi]*V_);
    for (int i = tid; i < 250; i += 256) ((float4*)prim[wi])[i] = src[i];
  }
  __syncthreads();

  const int wv = tid >> 6, lane = tid & 63;
  for (int l = wv; l < L_; l += 4) {
    float c0 = SrT[0][l];
    float cw[10];
    #pragma unroll
    for (int wi = 0; wi < 10; ++wi) cw[wi] = SrT[1+wi][l];
    float sv[16];
    float mx = -1e30f;
    #pragma unroll
    for (int jj = 0; jj < 16; ++jj) {
      int v = lane + 64*jj;
      float s = -1e30f;
      if (v < V_) {
        s = c0 * iv[v];
        #pragma unroll
        for (int wi = 0; wi < 10; ++wi) s += cw[wi]*prim[wi][v];
      }
      sv[jj] = s;
      mx = fmaxf(mx, s);
    }
    #pragma unroll
    for (int off = 32; off; off >>= 1) mx = fmaxf(mx, __shfl_xor(mx, off));
    float se = 0.f;
    #pragma unroll
    for (int jj = 0; jj < 16; ++jj) {
      int v = lane + 64*jj;
      if (v < V_) se += __expf(sv[jj] - mx);
    }
    #pragma unroll
    for (int off = 32; off; off >>= 1) se += __shfl_xor(se, off);
    if (lane == 0) lss[l] = mx + __logf(se);
  }
  __syncthreads();

  float* __restrict__ dst = out + (size_t)b*50000 + (size_t)v0*50;
  for (int e = tid; e < 125*50; e += 256) {
    const int v = e / 50, l = e - v*50;
    const int vg = v0 + v;
    float s = SrT[0][l]*iv[vg];
    #pragma unroll
    for (int wi = 0; wi < 10; ++wi) s += SrT[1+wi][l]*prim[wi][vg];
    dst[e] = s - lss[l];
  }
}

// ---------------------------------------------------------------------------
extern "C" void kernel_launch(void* const* d_in, const int* in_sizes, int n_in,
                              void* d_out, int out_size, void* d_ws, size_t ws_size,
                              hipStream_t stream)
{
  (void)in_sizes; (void)n_in; (void)out_size; (void)ws_size;
  const float* gate_emb = (const float*)d_in[0];
  const float* prog_emb = (const float*)d_in[1];
  const float* prim_emb = (const float*)d_in[2];
  const float* sk       = (const float*)d_in[3];
  const float* iv       = (const float*)d_in[4];
  const float* w_ih     = (const float*)d_in[5];
  const float* w_hh     = (const float*)d_in[6];
  const float* b_ih     = (const float*)d_in[7];
  const float* b_hh     = (const float*)d_in[8];
  const int*   instr    = (const int*)d_in[9];
  const int*   tacts    = (const int*)d_in[10];
  float* out = (float*)d_out;

  float* ws     = (float*)d_ws;
  float* S_buf  = ws;                          // 256*600 f32
  float* g01    = S_buf + B_*600;              // 5120 f32
  float* giv    = g01 + NW_*B_*2;              // 1,152,000 f32
  unsigned char* whhP = (unsigned char*)(giv + (size_t)V_*H3_);  // 147456 B
  unsigned char* whhS = whhP + 147456;                           // 294912 B
  _Float16* wih_h  = (_Float16*)(whhS + 294912);             // 1152*224 f16
  _Float16* prog_h = wih_h + (size_t)H3_*224;                // 200000 f16
  _Float16* hdump  = prog_h + (size_t)V_*P_;                 // 31*16*384*16 f16

  hipLaunchKernelGGL(prep_kernel, dim3(1024), dim3(256), 0, stream,
      gate_emb, prog_emb, w_ih, w_hh, instr, tacts,
      g01, whhP, whhS, wih_h, prog_h, out);

  hipLaunchKernelGGL(gi_gemm, dim3(63, 18), dim3(256), 0, stream,
      prog_h, wih_h, b_ih, giv);

  hipLaunchKernelGGL(steps_kernel, dim3(16), dim3(768), 0, stream,
      (const uint4*)whhP, (const uint4*)whhS, giv, g01, sk, b_hh, instr, hdump);

  hipLaunchKernelGGL(attnS_kernel, dim3(256), dim3(256), 0, stream,
      hdump, sk, g01, S_buf);

  hipLaunchKernelGGL(write_kernel, dim3(8, 256), dim3(256), 0, stream,
      S_buf, prim_emb, iv, instr, out);
}

// Round 10
// 339.526 us; speedup vs baseline: 1.3866x; 1.3866x over previous
//
#include <hip/hip_runtime.h>
#include <hip/hip_fp16.h>
#include <hip/hip_fp8.h>

#define B_ 256
#define V_ 1000
#define P_ 200
#define L_ 50
#define H_ 384
#define H3_ 1152
#define NW_ 10
#define OUT1_OFF 12800000

typedef _Float16 half8 __attribute__((ext_vector_type(8)));
typedef _Float16 half4_t __attribute__((ext_vector_type(4)));
typedef float floatx4 __attribute__((ext_vector_type(4)));

// ---------------------------------------------------------------------------
// prep: fp8 pair-packed w_hh in TWO regions:
//   whhP (LDS-persist, j=2):  byte i = ((w*18 + u)*64 + l)*16 + p*8 + e
//       u in [0,18): g=u/6, kap=u%6
//   whhR (VGPR-persist, j=0,1): byte i = ((w*36 + u)*64 + l)*16 + p*8 + e
//       u in [0,36): j=u/18, rem=u%18, g=rem/6, kap=rem%6
// Common: kc=2*kap+p; row = g*384 + 48w + 16j + (l&15);
//         col = kc*32 + (l>>4)*8 + e;   value = w_hh[row*H + col]
// ---------------------------------------------------------------------------
__global__ __launch_bounds__(256) void prep_kernel(
    const float* __restrict__ gate_emb, const float* __restrict__ prog_emb,
    const float* __restrict__ w_ih, const float* __restrict__ w_hh,
    const int* __restrict__ instr, const int* __restrict__ tacts,
    float* __restrict__ g01, unsigned char* __restrict__ whhP,
    unsigned char* __restrict__ whhR,
    _Float16* __restrict__ wih_h, _Float16* __restrict__ prog_h,
    float* __restrict__ out)
{
  const int stride = gridDim.x * blockDim.x;
  const int tid = blockIdx.x * blockDim.x + threadIdx.x;

  for (int i = tid; i < 147456; i += stride) {
    const int e = i & 7, p = (i >> 3) & 1, l = (i >> 4) & 63;
    const int q = i >> 10;                 // [0,144) = w*18+u
    const int u = q % 18, w = q / 18;
    const int g = u / 6, kap = u - 6*g;
    const int kc = 2*kap + p;
    const int row = g*384 + 48*w + 16*2 + (l & 15);
    const int col = kc*32 + (l >> 4)*8 + e;
    __hip_fp8_e4m3 qv(w_hh[row*H_ + col]);
    whhP[i] = qv.__x;
  }
  for (int i = tid; i < 294912; i += stride) {
    const int e = i & 7, p = (i >> 3) & 1, l = (i >> 4) & 63;
    const int q = i >> 10;                 // [0,288) = w*36+u
    const int u = q % 36, w = q / 36;
    const int j = u / 18, rem = u - 18*j;
    const int g = rem / 6, kap = rem - 6*g;
    const int kc = 2*kap + p;
    const int row = g*384 + 48*w + 16*j + (l & 15);
    const int col = kc*32 + (l >> 4)*8 + e;
    __hip_fp8_e4m3 qv(w_hh[row*H_ + col]);
    whhR[i] = qv.__x;
  }
  for (int i = tid; i < H3_*224; i += stride) {
    int r = i / 224, c = i - r*224;
    wih_h[i] = (_Float16)(c < P_ ? w_ih[r*P_ + c] : 0.f);
  }
  for (int i = tid; i < V_*P_; i += stride) prog_h[i] = (_Float16)prog_emb[i];
  for (int i = tid; i < NW_*B_; i += stride) {
    int w = i / B_, b = i - w*B_;
    int word = instr[(1+w)*B_ + b];
    float e0 = gate_emb[word*2], e1 = gate_emb[word*2+1];
    float m = fmaxf(e0, e1);
    float a = __expf(e0-m), c = __expf(e1-m);
    float inv = 1.f/(a+c);
    g01[i*2] = a*inv; g01[i*2+1] = c*inv;
  }
  for (int i = tid; i < B_*L_; i += stride) {
    int b = i / L_, l = i - b*L_;
    out[OUT1_OFF + i] = (float)tacts[(1+l)*B_ + b];
  }
}

// ---------------------------------------------------------------------------
// gi_gemm: giv[v][n] = program_emb[v] @ w_ih.T + b_ih   (vocab-wide, once)
// ---------------------------------------------------------------------------
__global__ __launch_bounds__(256) void gi_gemm(
    const _Float16* __restrict__ prog_h, const _Float16* __restrict__ wih_h,
    const float* __restrict__ b_ih, float* __restrict__ giv)
{
  __shared__ _Float16 pA[16][232];
  const int tid = threadIdx.x;
  const int v0 = blockIdx.x * 16;
  const int n0 = blockIdx.y * 64;

  for (int i = tid; i < 16*224; i += 256) {
    int r = i / 224, c = i - r*224;
    int v = v0 + r;
    _Float16 val = (_Float16)0.f;
    if (v < V_ && c < P_) val = prog_h[v*P_ + c];
    pA[r][c] = val;
  }
  __syncthreads();

  const int wave = tid >> 6, lane = tid & 63;
  const int m = lane & 15, kg = lane >> 4;
  const int n_t = n0 + wave*16;
  floatx4 acc = {0.f, 0.f, 0.f, 0.f};
  #pragma unroll
  for (int ks = 0; ks < 7; ++ks) {
    const int kk = ks*32 + kg*8;
    half8 av = *(const half8*)&pA[m][kk];
    half8 bv = *(const half8*)&wih_h[(n_t + m)*224 + kk];
    acc = __builtin_amdgcn_mfma_f32_16x16x32_f16(av, bv, acc, 0, 0, 0);
  }
  const int nn = n_t + m;
  const float bias = b_ih[nn];
  #pragma unroll
  for (int r = 0; r < 4; ++r) {
    int mm = v0 + kg*4 + r;
    if (mm < V_) giv[(size_t)mm*H3_ + nn] = acc[r] + bias;
  }
}

// ---------------------------------------------------------------------------
// steps: GRU recurrence, 16 blocks x 512 threads (8 waves, 2/SIMD, 256-VGPR
// budget). ENTIRE w_hh resident on-CU: 36 units/wave in NAMED registers
// (144 VGPRs) + 18 units/wave in LDS (144 KB). Zero VMEM loads in the steady
// loop. Output cols grouped in 3 j-slices (3 accs live at a time); per-slice
// GRU epilogue updates hreg in place; hA/hdump writes deferred past the
// read barrier. 2 raw lgkm barriers/step.
// ---------------------------------------------------------------------------
__global__ __launch_bounds__(512, 2) void steps_kernel(
    const uint4* __restrict__ whhPp, const uint4* __restrict__ whhRp,
    const float* __restrict__ giv, const float* __restrict__ g01,
    const float* __restrict__ keys, const float* __restrict__ bhh,
    const int* __restrict__ instr, _Float16* __restrict__ hdump)
{
  __shared__ uint4 ldsP[9216];             // 147456 B persistent weights (j=2)
  __shared__ unsigned long long hA[768];   // 6144 B fp8 h image

  const int bid = blockIdx.x, b0 = bid*16, tid = threadIdx.x;
  const int w = tid >> 6, lane = tid & 63, m_ = lane & 15, kg = lane >> 4;

  for (int i = tid; i < 9216; i += 512) ldsP[i] = whhPp[i];

  const uint4* __restrict__ rbase = whhRp + (size_t)w*36*64 + lane;

  float hreg[3][4];        // [j][r]: col 48w+16j+m_, batch kg*4+r
  float bb[9];             // [j*3+g]
  float gvv[4][9];         // [r][j*3+g]
  float g0r[4], g1r[4];

  #pragma unroll
  for (int j = 0; j < 3; ++j)
    #pragma unroll
    for (int g = 0; g < 3; ++g)
      bb[j*3+g] = bhh[g*384 + 48*w + 16*j + m_];

  // h0 = tile(scratch_keys[0], 3)
  #pragma unroll
  for (int j = 0; j < 3; ++j) {
    const float h0 = keys[(48*w + 16*j + m_) & 127];
    #pragma unroll
    for (int r = 0; r < 4; ++r) hreg[j][r] = h0;
  }

  // initial fp8 hA image + h dump slot 0
  #pragma unroll
  for (int j = 0; j < 3; ++j) {
    const int c = 48*w + 16*j + m_;
    const int base = (c >> 5)*512 + ((c >> 3) & 3)*128 + (c & 7);
    half4_t hv;
    #pragma unroll
    for (int r = 0; r < 4; ++r) {
      __hip_fp8_e4m3 q(hreg[j][r]);
      ((unsigned char*)hA)[base + (kg*4 + r)*8] = q.__x;
      hv[r] = (_Float16)hreg[j][r];
    }
    *(half4_t*)&hdump[(((size_t)0*16 + bid)*384 + c)*16 + kg*4] = hv;
  }

  // word-0 parameter loads
  {
    int4 wd4 = *(const int4*)&instr[(1+0)*B_ + b0 + kg*4];
    int wdr[4] = {wd4.x, wd4.y, wd4.z, wd4.w};
    #pragma unroll
    for (int r = 0; r < 4; ++r) {
      float2 gg = *(const float2*)&g01[(size_t)(b0 + kg*4 + r)*2];
      g0r[r] = gg.x; g1r[r] = gg.y;
    }
    #pragma unroll
    for (int r = 0; r < 4; ++r) {
      const float* gp = giv + (size_t)wdr[r]*H3_;
      #pragma unroll
      for (int j = 0; j < 3; ++j)
        #pragma unroll
        for (int g = 0; g < 3; ++g)
          gvv[r][j*3+g] = gp[g*384 + 48*w + 16*j + m_];
    }
  }

  // 36 persistent weight registers (144 VGPRs), loaded ONCE
  uint4 W00 = rbase[ 0*64], W01 = rbase[ 1*64], W02 = rbase[ 2*64];
  uint4 W03 = rbase[ 3*64], W04 = rbase[ 4*64], W05 = rbase[ 5*64];
  uint4 W06 = rbase[ 6*64], W07 = rbase[ 7*64], W08 = rbase[ 8*64];
  uint4 W09 = rbase[ 9*64], W10 = rbase[10*64], W11 = rbase[11*64];
  uint4 W12 = rbase[12*64], W13 = rbase[13*64], W14 = rbase[14*64];
  uint4 W15 = rbase[15*64], W16 = rbase[16*64], W17 = rbase[17*64];
  uint4 W18 = rbase[18*64], W19 = rbase[19*64], W20 = rbase[20*64];
  uint4 W21 = rbase[21*64], W22 = rbase[22*64], W23 = rbase[23*64];
  uint4 W24 = rbase[24*64], W25 = rbase[25*64], W26 = rbase[26*64];
  uint4 W27 = rbase[27*64], W28 = rbase[28*64], W29 = rbase[29*64];
  uint4 W30 = rbase[30*64], W31 = rbase[31*64], W32 = rbase[32*64];
  uint4 W33 = rbase[33*64], W34 = rbase[34*64], W35 = rbase[35*64];

  asm volatile("s_waitcnt lgkmcnt(0)\n\ts_barrier" ::: "memory");

#define LO64(W) ((long)((((unsigned long long)(W).y) << 32) | (W).x))
#define HI64(W) ((long)((((unsigned long long)(W).w) << 32) | (W).z))
#define KSTEP(KAP, WA, WB, WC) \
  a0 = hA[(2*(KAP))*64 + lane]; a1 = hA[(2*(KAP)+1)*64 + lane]; \
  acc0 = __builtin_amdgcn_mfma_f32_16x16x32_fp8_fp8((long)a0, LO64(WA), acc0, 0, 0, 0); \
  acc0 = __builtin_amdgcn_mfma_f32_16x16x32_fp8_fp8((long)a1, HI64(WA), acc0, 0, 0, 0); \
  acc1 = __builtin_amdgcn_mfma_f32_16x16x32_fp8_fp8((long)a0, LO64(WB), acc1, 0, 0, 0); \
  acc1 = __builtin_amdgcn_mfma_f32_16x16x32_fp8_fp8((long)a1, HI64(WB), acc1, 0, 0, 0); \
  acc2 = __builtin_amdgcn_mfma_f32_16x16x32_fp8_fp8((long)a0, LO64(WC), acc2, 0, 0, 0); \
  acc2 = __builtin_amdgcn_mfma_f32_16x16x32_fp8_fp8((long)a1, HI64(WC), acc2, 0, 0, 0);
#define KSTEPL(KAP) \
  { a0 = hA[(2*(KAP))*64 + lane]; a1 = hA[(2*(KAP)+1)*64 + lane]; \
    uint4 P0 = ldsP[(w*18 +      (KAP))*64 + lane]; \
    uint4 P1 = ldsP[(w*18 +  6 + (KAP))*64 + lane]; \
    uint4 P2 = ldsP[(w*18 + 12 + (KAP))*64 + lane]; \
    acc0 = __builtin_amdgcn_mfma_f32_16x16x32_fp8_fp8((long)a0, LO64(P0), acc0, 0, 0, 0); \
    acc0 = __builtin_amdgcn_mfma_f32_16x16x32_fp8_fp8((long)a1, HI64(P0), acc0, 0, 0, 0); \
    acc1 = __builtin_amdgcn_mfma_f32_16x16x32_fp8_fp8((long)a0, LO64(P1), acc1, 0, 0, 0); \
    acc1 = __builtin_amdgcn_mfma_f32_16x16x32_fp8_fp8((long)a1, HI64(P1), acc1, 0, 0, 0); \
    acc2 = __builtin_amdgcn_mfma_f32_16x16x32_fp8_fp8((long)a0, LO64(P2), acc2, 0, 0, 0); \
    acc2 = __builtin_amdgcn_mfma_f32_16x16x32_fp8_fp8((long)a1, HI64(P2), acc2, 0, 0, 0); }
#define EPI(J) \
  _Pragma("unroll") \
  for (int r = 0; r < 4; ++r) { \
    const float ghr = acc0[r] + bb[(J)*3+0]; \
    const float ghz = acc1[r] + bb[(J)*3+1]; \
    const float ghn = acc2[r] + bb[(J)*3+2]; \
    const float rg = 1.f/(1.f + __expf(-(gvv[r][(J)*3+0] + ghr))); \
    const float z  = 1.f/(1.f + __expf(-(gvv[r][(J)*3+1] + ghz))); \
    const float x2 = gvv[r][(J)*3+2] + rg*ghn; \
    const float nn = 2.f/(1.f + __expf(-2.f*x2)) - 1.f; \
    const float hold = hreg[(J)][r]; \
    const float hnew = (1.f - z)*nn + z*hold; \
    hreg[(J)][r] = g0r[r]*hold + g1r[r]*hnew; \
  }

  #pragma unroll 1
  for (int t = 0; t < 30; ++t) {
    unsigned long long a0, a1;
    floatx4 acc0, acc1, acc2;

    // ---- j = 0 (register weights) ----
    acc0 = (floatx4){0.f,0.f,0.f,0.f}; acc1 = acc0; acc2 = acc0;
    KSTEP(0, W00, W06, W12) KSTEP(1, W01, W07, W13) KSTEP(2, W02, W08, W14)
    KSTEP(3, W03, W09, W15) KSTEP(4, W04, W10, W16) KSTEP(5, W05, W11, W17)
    EPI(0)
    // ---- j = 1 (register weights) ----
    acc0 = (floatx4){0.f,0.f,0.f,0.f}; acc1 = acc0; acc2 = acc0;
    KSTEP(0, W18, W24, W30) KSTEP(1, W19, W25, W31) KSTEP(2, W20, W26, W32)
    KSTEP(3, W21, W27, W33) KSTEP(4, W22, W28, W34) KSTEP(5, W23, W29, W35)
    EPI(1)
    // ---- j = 2 (LDS weights) ----
    acc0 = (floatx4){0.f,0.f,0.f,0.f}; acc1 = acc0; acc2 = acc0;
    KSTEPL(0) KSTEPL(1) KSTEPL(2) KSTEPL(3) KSTEPL(4) KSTEPL(5)
    EPI(2)

    asm volatile("s_waitcnt lgkmcnt(0)\n\ts_barrier" ::: "memory"); // hA reads done

    // ---- new fp8 hA image + h dump slot t+1 ----
    #pragma unroll
    for (int j = 0; j < 3; ++j) {
      const int c = 48*w + 16*j + m_;
      const int base = (c >> 5)*512 + ((c >> 3) & 3)*128 + (c & 7);
      half4_t hv;
      #pragma unroll
      for (int r = 0; r < 4; ++r) {
        __hip_fp8_e4m3 q(hreg[j][r]);
        ((unsigned char*)hA)[base + (kg*4 + r)*8] = q.__x;
        hv[r] = (_Float16)hreg[j][r];
      }
      *(half4_t*)&hdump[(((size_t)(t+1)*16 + bid)*384 + c)*16 + kg*4] = hv;
    }

    // ---- word-boundary loads for next word ----
    if (t % 3 == 2) {
      const int wi = (t/3 + 1 < 10) ? t/3 + 1 : 9;
      int4 wd4 = *(const int4*)&instr[(1+wi)*B_ + b0 + kg*4];
      int wdr[4] = {wd4.x, wd4.y, wd4.z, wd4.w};
      #pragma unroll
      for (int r = 0; r < 4; ++r) {
        float2 gg = *(const float2*)&g01[((size_t)wi*B_ + b0 + kg*4 + r)*2];
        g0r[r] = gg.x; g1r[r] = gg.y;
      }
      #pragma unroll
      for (int r = 0; r < 4; ++r) {
        const float* gp = giv + (size_t)wdr[r]*H3_;
        #pragma unroll
        for (int j = 0; j < 3; ++j)
          #pragma unroll
          for (int g = 0; g < 3; ++g)
            gvv[r][j*3+g] = gp[g*384 + 48*w + 16*j + m_];
      }
    }

    asm volatile("s_waitcnt lgkmcnt(0)\n\ts_barrier" ::: "memory"); // hA writes
  }
  asm volatile("s_waitcnt vmcnt(0) lgkmcnt(0)" ::: "memory");
#undef KSTEP
#undef KSTEPL
#undef EPI
#undef LO64
#undef HI64
}

// ---------------------------------------------------------------------------
// attnS: decoupled attention/S recurrence, one block per batch element.
// Phase 1: all 60 score rows in parallel; phase 2: 30-step S recurrence.
// ---------------------------------------------------------------------------
__global__ __launch_bounds__(256) void attnS_kernel(
    const _Float16* __restrict__ hdump, const float* __restrict__ keys,
    const float* __restrict__ g01, float* __restrict__ S_buf)
{
  __shared__ float keysT[128][52];   // [k][l]
  __shared__ float hT[30][256];      // h cols 128..383 per step
  __shared__ float sc[30][2][52];    // softmax probs
  __shared__ float Sr[50][13];
  __shared__ float g0a[10], g1a[10];
  __shared__ float nvs[12];

  const int b = blockIdx.x, g = b >> 4, bl = b & 15;
  const int tid = threadIdx.x, wv = tid >> 6, lane = tid & 63;

  for (int i = tid; i < 128*L_; i += 256) {
    int k = i / L_, l = i - k*L_;
    keysT[k][l] = keys[l*128 + k];
  }
  for (int i = tid; i < 30*256; i += 256) {
    int t = i >> 8, c = i & 255;
    hT[t][c] = (float)hdump[(((size_t)t*16 + g)*384 + 128 + c)*16 + bl];
  }
  for (int i = tid; i < 550; i += 256) Sr[i/11][i%11] = ((i % 11) == 0) ? 1.f : 0.f;
  if (tid < NW_) {
    float2 gg = *(const float2*)&g01[((size_t)tid*B_ + b)*2];
    g0a[tid] = gg.x; g1a[tid] = gg.y;
  }
  __syncthreads();

  // ---- phase 1: 60 score rows, 15 per wave ----
  for (int row = wv; row < 60; row += 4) {
    const int t = row >> 1, ty = row & 1;
    float s = 0.f;
    if (lane < L_) {
      #pragma unroll 8
      for (int k = 0; k < 128; ++k)
        s += hT[t][ty*128 + k] * keysT[k][lane];
    }
    float val = (lane < L_) ? s : -1e30f;
    float mx = val;
    #pragma unroll
    for (int off = 32; off; off >>= 1) mx = fmaxf(mx, __shfl_xor(mx, off));
    float e = (lane < L_) ? __expf(val - mx) : 0.f;
    float sm = e;
    #pragma unroll
    for (int off = 32; off; off >>= 1) sm += __shfl_xor(sm, off);
    if (lane < L_) sc[t][ty][lane] = e / sm;
  }
  __syncthreads();

  // ---- phase 2: S recurrence ----
  for (int t = 0; t < 30; ++t) {
    const int widx = t / 3;
    if (tid < 11) {
      float rv = 0.f;
      #pragma unroll 5
      for (int l = 0; l < L_; ++l) rv += sc[t][0][l] * Sr[l][tid];
      nvs[tid] = g1a[widx]*rv + ((tid == 1 + widx) ? g0a[widx] : 0.f);
    }
    __syncthreads();
    for (int i = tid; i < 550; i += 256) {
      const int l = i / 11, j = i - l*11;
      const float wm = sc[t][1][l];
      Sr[l][j] = wm*nvs[j] + (1.f - wm)*Sr[l][j];
    }
    __syncthreads();
  }

  for (int i = tid; i < 550; i += 256) {
    const int l = i / 11, j = i - l*11;
    S_buf[(size_t)b*600 + l*12 + j] = Sr[l][j];
  }
}

// ---------------------------------------------------------------------------
// epi: merged lse + write, ONE block per batch element (prim read once).
// lse over 1000-v reconstruction, then 50,000 contiguous coalesced stores.
// ---------------------------------------------------------------------------
__global__ __launch_bounds__(512) void epi_kernel(
    const float* __restrict__ S_buf, const float* __restrict__ prim_emb,
    const float* __restrict__ iv_g, const int* __restrict__ instr,
    float* __restrict__ out)
{
  __shared__ float prim[10][1000];
  __shared__ float iv[1000];
  __shared__ float SrT[11][52];
  __shared__ float lss[52];
  __shared__ int wds[10];

  const int b = blockIdx.x;
  const int tid = threadIdx.x;

  if (tid < 10) wds[tid] = instr[(1+tid)*B_ + b];
  for (int i = tid; i < 550; i += 512) {
    int l = i / 11, j = i - l*11;
    SrT[j][l] = S_buf[(size_t)b*600 + l*12 + j];
  }
  for (int i = tid; i < 250; i += 512) ((float4*)iv)[i] = ((const float4*)iv_g)[i];
  __syncthreads();
  for (int wi = 0; wi < 10; ++wi) {
    const float4* __restrict__ src = (const float4*)(prim_emb + (size_t)wds[wi]*V_);
    for (int i = tid; i < 250; i += 512) ((float4*)prim[wi])[i] = src[i];
  }
  __syncthreads();

  const int wv = tid >> 6, lane = tid & 63;
  for (int l = wv; l < L_; l += 8) {
    float c0 = SrT[0][l];
    float cw[10];
    #pragma unroll
    for (int wi = 0; wi < 10; ++wi) cw[wi] = SrT[1+wi][l];
    float sv[16];
    float mx = -1e30f;
    #pragma unroll
    for (int jj = 0; jj < 16; ++jj) {
      int v = lane + 64*jj;
      float s = -1e30f;
      if (v < V_) {
        s = c0 * iv[v];
        #pragma unroll
        for (int wi = 0; wi < 10; ++wi) s += cw[wi]*prim[wi][v];
      }
      sv[jj] = s;
      mx = fmaxf(mx, s);
    }
    #pragma unroll
    for (int off = 32; off; off >>= 1) mx = fmaxf(mx, __shfl_xor(mx, off));
    float se = 0.f;
    #pragma unroll
    for (int jj = 0; jj < 16; ++jj) {
      int v = lane + 64*jj;
      if (v < V_) se += __expf(sv[jj] - mx);
    }
    #pragma unroll
    for (int off = 32; off; off >>= 1) se += __shfl_xor(se, off);
    if (lane == 0) lss[l] = mx + __logf(se);
  }
  __syncthreads();

  float* __restrict__ dst = out + (size_t)b*50000;
  for (int e = tid; e < 50000; e += 512) {
    const int v = e / 50, l = e - v*50;
    float s = SrT[0][l]*iv[v];
    #pragma unroll
    for (int wi = 0; wi < 10; ++wi) s += SrT[1+wi][l]*prim[wi][v];
    dst[e] = s - lss[l];
  }
}

// ---------------------------------------------------------------------------
extern "C" void kernel_launch(void* const* d_in, const int* in_sizes, int n_in,
                              void* d_out, int out_size, void* d_ws, size_t ws_size,
                              hipStream_t stream)
{
  (void)in_sizes; (void)n_in; (void)out_size; (void)ws_size;
  const float* gate_emb = (const float*)d_in[0];
  const float* prog_emb = (const float*)d_in[1];
  const float* prim_emb = (const float*)d_in[2];
  const float* sk       = (const float*)d_in[3];
  const float* iv       = (const float*)d_in[4];
  const float* w_ih     = (const float*)d_in[5];
  const float* w_hh     = (const float*)d_in[6];
  const float* b_ih     = (const float*)d_in[7];
  const float* b_hh     = (const float*)d_in[8];
  const int*   instr    = (const int*)d_in[9];
  const int*   tacts    = (const int*)d_in[10];
  float* out = (float*)d_out;

  float* ws     = (float*)d_ws;
  float* S_buf  = ws;                          // 256*600 f32
  float* g01    = S_buf + B_*600;              // 5120 f32
  float* giv    = g01 + NW_*B_*2;              // 1,152,000 f32
  unsigned char* whhP = (unsigned char*)(giv + (size_t)V_*H3_);  // 147456 B
  unsigned char* whhR = whhP + 147456;                           // 294912 B
  _Float16* wih_h  = (_Float16*)(whhR + 294912);             // 1152*224 f16
  _Float16* prog_h = wih_h + (size_t)H3_*224;                // 200000 f16
  _Float16* hdump  = prog_h + (size_t)V_*P_;                 // 31*16*384*16 f16

  hipLaunchKernelGGL(prep_kernel, dim3(1024), dim3(256), 0, stream,
      gate_emb, prog_emb, w_ih, w_hh, instr, tacts,
      g01, whhP, whhR, wih_h, prog_h, out);

  hipLaunchKernelGGL(gi_gemm, dim3(63, 18), dim3(256), 0, stream,
      prog_h, wih_h, b_ih, giv);

  hipLaunchKernelGGL(steps_kernel, dim3(16), dim3(512), 0, stream,
      (const uint4*)whhP, (const uint4*)whhR, giv, g01, sk, b_hh, instr, hdump);

  hipLaunchKernelGGL(attnS_kernel, dim3(256), dim3(256), 0, stream,
      hdump, sk, g01, S_buf);

  hipLaunchKernelGGL(epi_kernel, dim3(256), dim3(512), 0, stream,
      S_buf, prim_emb, iv, instr, out);
}

// Round 11
// 299.177 us; speedup vs baseline: 1.5736x; 1.1349x over previous
//
#include <hip/hip_runtime.h>
#include <hip/hip_fp16.h>
#include <hip/hip_fp8.h>

#define B_ 256
#define V_ 1000
#define P_ 200
#define L_ 50
#define H_ 384
#define H3_ 1152
#define NW_ 10
#define OUT1_OFF 12800000

typedef _Float16 half8 __attribute__((ext_vector_type(8)));
typedef _Float16 half4_t __attribute__((ext_vector_type(4)));
typedef _Float16 half2_t __attribute__((ext_vector_type(2)));
typedef float floatx4 __attribute__((ext_vector_type(4)));

// ---------------------------------------------------------------------------
// prep: fp8 pair-packed w_hh in TWO regions (identical layout to round 10):
//   whhP (LDS-persist, j=2):  byte i = ((w*18 + u)*64 + l)*16 + p*8 + e
//   whhR (VGPR-persist, j=0,1): byte i = ((w*36 + u)*64 + l)*16 + p*8 + e
// ---------------------------------------------------------------------------
__global__ __launch_bounds__(256) void prep_kernel(
    const float* __restrict__ gate_emb, const float* __restrict__ prog_emb,
    const float* __restrict__ w_ih, const float* __restrict__ w_hh,
    const int* __restrict__ instr, const int* __restrict__ tacts,
    float* __restrict__ g01, unsigned char* __restrict__ whhP,
    unsigned char* __restrict__ whhR,
    _Float16* __restrict__ wih_h, _Float16* __restrict__ prog_h,
    float* __restrict__ out)
{
  const int stride = gridDim.x * blockDim.x;
  const int tid = blockIdx.x * blockDim.x + threadIdx.x;

  for (int i = tid; i < 147456; i += stride) {
    const int e = i & 7, p = (i >> 3) & 1, l = (i >> 4) & 63;
    const int q = i >> 10;
    const int u = q % 18, w = q / 18;
    const int g = u / 6, kap = u - 6*g;
    const int kc = 2*kap + p;
    const int row = g*384 + 48*w + 16*2 + (l & 15);
    const int col = kc*32 + (l >> 4)*8 + e;
    __hip_fp8_e4m3 qv(w_hh[row*H_ + col]);
    whhP[i] = qv.__x;
  }
  for (int i = tid; i < 294912; i += stride) {
    const int e = i & 7, p = (i >> 3) & 1, l = (i >> 4) & 63;
    const int q = i >> 10;
    const int u = q % 36, w = q / 36;
    const int j = u / 18, rem = u - 18*j;
    const int g = rem / 6, kap = rem - 6*g;
    const int kc = 2*kap + p;
    const int row = g*384 + 48*w + 16*j + (l & 15);
    const int col = kc*32 + (l >> 4)*8 + e;
    __hip_fp8_e4m3 qv(w_hh[row*H_ + col]);
    whhR[i] = qv.__x;
  }
  for (int i = tid; i < H3_*224; i += stride) {
    int r = i / 224, c = i - r*224;
    wih_h[i] = (_Float16)(c < P_ ? w_ih[r*P_ + c] : 0.f);
  }
  for (int i = tid; i < V_*P_; i += stride) prog_h[i] = (_Float16)prog_emb[i];
  for (int i = tid; i < NW_*B_; i += stride) {
    int w = i / B_, b = i - w*B_;
    int word = instr[(1+w)*B_ + b];
    float e0 = gate_emb[word*2], e1 = gate_emb[word*2+1];
    float m = fmaxf(e0, e1);
    float a = __expf(e0-m), c = __expf(e1-m);
    float inv = 1.f/(a+c);
    g01[i*2] = a*inv; g01[i*2+1] = c*inv;
  }
  for (int i = tid; i < B_*L_; i += stride) {
    int b = i / L_, l = i - b*L_;
    out[OUT1_OFF + i] = (float)tacts[(1+l)*B_ + b];
  }
}

// ---------------------------------------------------------------------------
// gi_gemm: giv[v][n] = program_emb[v] @ w_ih.T + b_ih (+ b_hh for r/z gates,
// folded here so the steps kernel only needs the n-gate b_hh).
// ---------------------------------------------------------------------------
__global__ __launch_bounds__(256) void gi_gemm(
    const _Float16* __restrict__ prog_h, const _Float16* __restrict__ wih_h,
    const float* __restrict__ b_ih, const float* __restrict__ b_hh,
    float* __restrict__ giv)
{
  __shared__ _Float16 pA[16][232];
  const int tid = threadIdx.x;
  const int v0 = blockIdx.x * 16;
  const int n0 = blockIdx.y * 64;

  for (int i = tid; i < 16*224; i += 256) {
    int r = i / 224, c = i - r*224;
    int v = v0 + r;
    _Float16 val = (_Float16)0.f;
    if (v < V_ && c < P_) val = prog_h[v*P_ + c];
    pA[r][c] = val;
  }
  __syncthreads();

  const int wave = tid >> 6, lane = tid & 63;
  const int m = lane & 15, kg = lane >> 4;
  const int n_t = n0 + wave*16;
  floatx4 acc = {0.f, 0.f, 0.f, 0.f};
  #pragma unroll
  for (int ks = 0; ks < 7; ++ks) {
    const int kk = ks*32 + kg*8;
    half8 av = *(const half8*)&pA[m][kk];
    half8 bv = *(const half8*)&wih_h[(n_t + m)*224 + kk];
    acc = __builtin_amdgcn_mfma_f32_16x16x32_f16(av, bv, acc, 0, 0, 0);
  }
  const int nn = n_t + m;
  const float bias = b_ih[nn] + (nn < 768 ? b_hh[nn] : 0.f);
  #pragma unroll
  for (int r = 0; r < 4; ++r) {
    int mm = v0 + kg*4 + r;
    if (mm < V_) giv[(size_t)mm*H3_ + nn] = acc[r] + bias;
  }
}

// ---------------------------------------------------------------------------
// steps: GRU recurrence, 16 blocks x 512 threads (8 waves, 2/SIMD, 256-VGPR
// cap). ENTIRE w_hh on-CU: 36 units/wave PINNED in registers via empty asm
// (rematerialization blocked) + 18 units/wave in LDS. Zero VMEM loads in the
// steady loop. gi values held as f16 half2 pairs; b_hh r/z folded into giv.
// ---------------------------------------------------------------------------
__global__ __launch_bounds__(512, 2) void steps_kernel(
    const uint4* __restrict__ whhPp, const uint4* __restrict__ whhRp,
    const float* __restrict__ giv, const float* __restrict__ g01,
    const float* __restrict__ keys, const float* __restrict__ bhh,
    const int* __restrict__ instr, _Float16* __restrict__ hdump)
{
  __shared__ uint4 ldsP[9216];             // 147456 B persistent weights (j=2)
  __shared__ unsigned long long hA[768];   // 6144 B fp8 h image

  const int bid = blockIdx.x, b0 = bid*16, tid = threadIdx.x;
  const int w = tid >> 6, lane = tid & 63, m_ = lane & 15, kg = lane >> 4;

  for (int i = tid; i < 9216; i += 512) ldsP[i] = whhPp[i];

  const uint4* __restrict__ rbase = whhRp + (size_t)w*36*64 + lane;

  float hreg[3][4];        // [j][r]: col 48w+16j+m_, batch kg*4+r
  float bbn[3];            // n-gate b_hh only
  half2_t gvh[18];         // gi values, f16 pairs, flat f = r*9+j*3+g
  float g0r[4], g1r[4];

  #pragma unroll
  for (int j = 0; j < 3; ++j) bbn[j] = bhh[768 + 48*w + 16*j + m_];

  // h0 = tile(scratch_keys[0], 3)
  #pragma unroll
  for (int j = 0; j < 3; ++j) {
    const float h0 = keys[(48*w + 16*j + m_) & 127];
    #pragma unroll
    for (int r = 0; r < 4; ++r) hreg[j][r] = h0;
  }

  // initial fp8 hA image + h dump slot 0
  #pragma unroll
  for (int j = 0; j < 3; ++j) {
    const int c = 48*w + 16*j + m_;
    const int base = (c >> 5)*512 + ((c >> 3) & 3)*128 + (c & 7);
    half4_t hv;
    #pragma unroll
    for (int r = 0; r < 4; ++r) {
      __hip_fp8_e4m3 q(hreg[j][r]);
      ((unsigned char*)hA)[base + (kg*4 + r)*8] = q.__x;
      hv[r] = (_Float16)hreg[j][r];
    }
    *(half4_t*)&hdump[(((size_t)0*16 + bid)*384 + c)*16 + kg*4] = hv;
  }

  // word-0 parameter loads
  {
    int4 wd4 = *(const int4*)&instr[(1+0)*B_ + b0 + kg*4];
    int wdr[4] = {wd4.x, wd4.y, wd4.z, wd4.w};
    #pragma unroll
    for (int r = 0; r < 4; ++r) {
      float2 gg = *(const float2*)&g01[(size_t)(b0 + kg*4 + r)*2];
      g0r[r] = gg.x; g1r[r] = gg.y;
    }
    #pragma unroll
    for (int r = 0; r < 4; ++r) {
      const float* gp = giv + (size_t)wdr[r]*H3_;
      #pragma unroll
      for (int j = 0; j < 3; ++j)
        #pragma unroll
        for (int g = 0; g < 3; ++g) {
          const int f = r*9 + j*3 + g;
          gvh[f >> 1][f & 1] = (_Float16)gp[g*384 + 48*w + 16*j + m_];
        }
    }
  }

  // 36 persistent weight registers (144 VGPRs), loaded ONCE and PINNED
  uint4 W00 = rbase[ 0*64], W01 = rbase[ 1*64], W02 = rbase[ 2*64];
  uint4 W03 = rbase[ 3*64], W04 = rbase[ 4*64], W05 = rbase[ 5*64];
  uint4 W06 = rbase[ 6*64], W07 = rbase[ 7*64], W08 = rbase[ 8*64];
  uint4 W09 = rbase[ 9*64], W10 = rbase[10*64], W11 = rbase[11*64];
  uint4 W12 = rbase[12*64], W13 = rbase[13*64], W14 = rbase[14*64];
  uint4 W15 = rbase[15*64], W16 = rbase[16*64], W17 = rbase[17*64];
  uint4 W18 = rbase[18*64], W19 = rbase[19*64], W20 = rbase[20*64];
  uint4 W21 = rbase[21*64], W22 = rbase[22*64], W23 = rbase[23*64];
  uint4 W24 = rbase[24*64], W25 = rbase[25*64], W26 = rbase[26*64];
  uint4 W27 = rbase[27*64], W28 = rbase[28*64], W29 = rbase[29*64];
  uint4 W30 = rbase[30*64], W31 = rbase[31*64], W32 = rbase[32*64];
  uint4 W33 = rbase[33*64], W34 = rbase[34*64], W35 = rbase[35*64];

#define PIN4(W) asm volatile("" : "+v"(W.x), "+v"(W.y), "+v"(W.z), "+v"(W.w))
  PIN4(W00); PIN4(W01); PIN4(W02); PIN4(W03); PIN4(W04); PIN4(W05);
  PIN4(W06); PIN4(W07); PIN4(W08); PIN4(W09); PIN4(W10); PIN4(W11);
  PIN4(W12); PIN4(W13); PIN4(W14); PIN4(W15); PIN4(W16); PIN4(W17);
  PIN4(W18); PIN4(W19); PIN4(W20); PIN4(W21); PIN4(W22); PIN4(W23);
  PIN4(W24); PIN4(W25); PIN4(W26); PIN4(W27); PIN4(W28); PIN4(W29);
  PIN4(W30); PIN4(W31); PIN4(W32); PIN4(W33); PIN4(W34); PIN4(W35);
#undef PIN4

  asm volatile("s_waitcnt lgkmcnt(0)\n\ts_barrier" ::: "memory");

#define LO64(W) ((long)((((unsigned long long)(W).y) << 32) | (W).x))
#define HI64(W) ((long)((((unsigned long long)(W).w) << 32) | (W).z))
#define GVF(F) ((float)gvh[(F) >> 1][(F) & 1])
#define KSTEP(KAP, WA, WB, WC) \
  a0 = hA[(2*(KAP))*64 + lane]; a1 = hA[(2*(KAP)+1)*64 + lane]; \
  acc0 = __builtin_amdgcn_mfma_f32_16x16x32_fp8_fp8((long)a0, LO64(WA), acc0, 0, 0, 0); \
  acc0 = __builtin_amdgcn_mfma_f32_16x16x32_fp8_fp8((long)a1, HI64(WA), acc0, 0, 0, 0); \
  acc1 = __builtin_amdgcn_mfma_f32_16x16x32_fp8_fp8((long)a0, LO64(WB), acc1, 0, 0, 0); \
  acc1 = __builtin_amdgcn_mfma_f32_16x16x32_fp8_fp8((long)a1, HI64(WB), acc1, 0, 0, 0); \
  acc2 = __builtin_amdgcn_mfma_f32_16x16x32_fp8_fp8((long)a0, LO64(WC), acc2, 0, 0, 0); \
  acc2 = __builtin_amdgcn_mfma_f32_16x16x32_fp8_fp8((long)a1, HI64(WC), acc2, 0, 0, 0);
#define KSTEPL(KAP) \
  { a0 = hA[(2*(KAP))*64 + lane]; a1 = hA[(2*(KAP)+1)*64 + lane]; \
    uint4 P0 = ldsP[(w*18 +      (KAP))*64 + lane]; \
    uint4 P1 = ldsP[(w*18 +  6 + (KAP))*64 + lane]; \
    uint4 P2 = ldsP[(w*18 + 12 + (KAP))*64 + lane]; \
    acc0 = __builtin_amdgcn_mfma_f32_16x16x32_fp8_fp8((long)a0, LO64(P0), acc0, 0, 0, 0); \
    acc0 = __builtin_amdgcn_mfma_f32_16x16x32_fp8_fp8((long)a1, HI64(P0), acc0, 0, 0, 0); \
    acc1 = __builtin_amdgcn_mfma_f32_16x16x32_fp8_fp8((long)a0, LO64(P1), acc1, 0, 0, 0); \
    acc1 = __builtin_amdgcn_mfma_f32_16x16x32_fp8_fp8((long)a1, HI64(P1), acc1, 0, 0, 0); \
    acc2 = __builtin_amdgcn_mfma_f32_16x16x32_fp8_fp8((long)a0, LO64(P2), acc2, 0, 0, 0); \
    acc2 = __builtin_amdgcn_mfma_f32_16x16x32_fp8_fp8((long)a1, HI64(P2), acc2, 0, 0, 0); }
#define EPI(J) \
  _Pragma("unroll") \
  for (int r = 0; r < 4; ++r) { \
    const float rg = 1.f/(1.f + __expf(-(GVF(r*9+(J)*3+0) + acc0[r]))); \
    const float z  = 1.f/(1.f + __expf(-(GVF(r*9+(J)*3+1) + acc1[r]))); \
    const float x2 = GVF(r*9+(J)*3+2) + rg*(acc2[r] + bbn[(J)]); \
    const float nn = 2.f/(1.f + __expf(-2.f*x2)) - 1.f; \
    const float hold = hreg[(J)][r]; \
    const float hnew = (1.f - z)*nn + z*hold; \
    hreg[(J)][r] = g0r[r]*hold + g1r[r]*hnew; \
  }

  #pragma unroll 1
  for (int t = 0; t < 30; ++t) {
    unsigned long long a0, a1;
    floatx4 acc0, acc1, acc2;

    // ---- j = 0 (register weights) ----
    acc0 = (floatx4){0.f,0.f,0.f,0.f}; acc1 = acc0; acc2 = acc0;
    KSTEP(0, W00, W06, W12) KSTEP(1, W01, W07, W13) KSTEP(2, W02, W08, W14)
    KSTEP(3, W03, W09, W15) KSTEP(4, W04, W10, W16) KSTEP(5, W05, W11, W17)
    EPI(0)
    // ---- j = 1 (register weights) ----
    acc0 = (floatx4){0.f,0.f,0.f,0.f}; acc1 = acc0; acc2 = acc0;
    KSTEP(0, W18, W24, W30) KSTEP(1, W19, W25, W31) KSTEP(2, W20, W26, W32)
    KSTEP(3, W21, W27, W33) KSTEP(4, W22, W28, W34) KSTEP(5, W23, W29, W35)
    EPI(1)
    // ---- j = 2 (LDS weights) ----
    acc0 = (floatx4){0.f,0.f,0.f,0.f}; acc1 = acc0; acc2 = acc0;
    KSTEPL(0) KSTEPL(1) KSTEPL(2) KSTEPL(3) KSTEPL(4) KSTEPL(5)
    EPI(2)

    asm volatile("s_waitcnt lgkmcnt(0)\n\ts_barrier" ::: "memory"); // hA reads done

    // ---- new fp8 hA image + h dump slot t+1 ----
    #pragma unroll
    for (int j = 0; j < 3; ++j) {
      const int c = 48*w + 16*j + m_;
      const int base = (c >> 5)*512 + ((c >> 3) & 3)*128 + (c & 7);
      half4_t hv;
      #pragma unroll
      for (int r = 0; r < 4; ++r) {
        __hip_fp8_e4m3 q(hreg[j][r]);
        ((unsigned char*)hA)[base + (kg*4 + r)*8] = q.__x;
        hv[r] = (_Float16)hreg[j][r];
      }
      *(half4_t*)&hdump[(((size_t)(t+1)*16 + bid)*384 + c)*16 + kg*4] = hv;
    }

    // ---- word-boundary loads for next word ----
    if (t % 3 == 2) {
      const int wi = (t/3 + 1 < 10) ? t/3 + 1 : 9;
      int4 wd4 = *(const int4*)&instr[(1+wi)*B_ + b0 + kg*4];
      int wdr[4] = {wd4.x, wd4.y, wd4.z, wd4.w};
      #pragma unroll
      for (int r = 0; r < 4; ++r) {
        float2 gg = *(const float2*)&g01[((size_t)wi*B_ + b0 + kg*4 + r)*2];
        g0r[r] = gg.x; g1r[r] = gg.y;
      }
      #pragma unroll
      for (int r = 0; r < 4; ++r) {
        const float* gp = giv + (size_t)wdr[r]*H3_;
        #pragma unroll
        for (int j = 0; j < 3; ++j)
          #pragma unroll
          for (int g = 0; g < 3; ++g) {
            const int f = r*9 + j*3 + g;
            gvh[f >> 1][f & 1] = (_Float16)gp[g*384 + 48*w + 16*j + m_];
          }
      }
    }

    asm volatile("s_waitcnt lgkmcnt(0)\n\ts_barrier" ::: "memory"); // hA writes
  }
  asm volatile("s_waitcnt vmcnt(0) lgkmcnt(0)" ::: "memory");
#undef KSTEP
#undef KSTEPL
#undef EPI
#undef GVF
#undef LO64
#undef HI64
}

// ---------------------------------------------------------------------------
// attnS: decoupled attention/S recurrence, one block per batch element.
// ---------------------------------------------------------------------------
__global__ __launch_bounds__(256) void attnS_kernel(
    const _Float16* __restrict__ hdump, const float* __restrict__ keys,
    const float* __restrict__ g01, float* __restrict__ S_buf)
{
  __shared__ float keysT[128][52];   // [k][l]
  __shared__ float hT[30][256];      // h cols 128..383 per step
  __shared__ float sc[30][2][52];    // softmax probs
  __shared__ float Sr[50][13];
  __shared__ float g0a[10], g1a[10];
  __shared__ float nvs[12];

  const int b = blockIdx.x, g = b >> 4, bl = b & 15;
  const int tid = threadIdx.x, wv = tid >> 6, lane = tid & 63;

  for (int i = tid; i < 128*L_; i += 256) {
    int k = i / L_, l = i - k*L_;
    keysT[k][l] = keys[l*128 + k];
  }
  for (int i = tid; i < 30*256; i += 256) {
    int t = i >> 8, c = i & 255;
    hT[t][c] = (float)hdump[(((size_t)t*16 + g)*384 + 128 + c)*16 + bl];
  }
  for (int i = tid; i < 550; i += 256) Sr[i/11][i%11] = ((i % 11) == 0) ? 1.f : 0.f;
  if (tid < NW_) {
    float2 gg = *(const float2*)&g01[((size_t)tid*B_ + b)*2];
    g0a[tid] = gg.x; g1a[tid] = gg.y;
  }
  __syncthreads();

  // ---- phase 1: 60 score rows, 15 per wave ----
  for (int row = wv; row < 60; row += 4) {
    const int t = row >> 1, ty = row & 1;
    float s = 0.f;
    if (lane < L_) {
      #pragma unroll 8
      for (int k = 0; k < 128; ++k)
        s += hT[t][ty*128 + k] * keysT[k][lane];
    }
    float val = (lane < L_) ? s : -1e30f;
    float mx = val;
    #pragma unroll
    for (int off = 32; off; off >>= 1) mx = fmaxf(mx, __shfl_xor(mx, off));
    float e = (lane < L_) ? __expf(val - mx) : 0.f;
    float sm = e;
    #pragma unroll
    for (int off = 32; off; off >>= 1) sm += __shfl_xor(sm, off);
    if (lane < L_) sc[t][ty][lane] = e / sm;
  }
  __syncthreads();

  // ---- phase 2: S recurrence ----
  for (int t = 0; t < 30; ++t) {
    const int widx = t / 3;
    if (tid < 11) {
      float rv = 0.f;
      #pragma unroll 5
      for (int l = 0; l < L_; ++l) rv += sc[t][0][l] * Sr[l][tid];
      nvs[tid] = g1a[widx]*rv + ((tid == 1 + widx) ? g0a[widx] : 0.f);
    }
    __syncthreads();
    for (int i = tid; i < 550; i += 256) {
      const int l = i / 11, j = i - l*11;
      const float wm = sc[t][1][l];
      Sr[l][j] = wm*nvs[j] + (1.f - wm)*Sr[l][j];
    }
    __syncthreads();
  }

  for (int i = tid; i < 550; i += 256) {
    const int l = i / 11, j = i - l*11;
    S_buf[(size_t)b*600 + l*12 + j] = Sr[l][j];
  }
}

// ---------------------------------------------------------------------------
// epi: merged lse + write, ONE block per batch element.
// ---------------------------------------------------------------------------
__global__ __launch_bounds__(512) void epi_kernel(
    const float* __restrict__ S_buf, const float* __restrict__ prim_emb,
    const float* __restrict__ iv_g, const int* __restrict__ instr,
    float* __restrict__ out)
{
  __shared__ float prim[10][1000];
  __shared__ float iv[1000];
  __shared__ float SrT[11][52];
  __shared__ float lss[52];
  __shared__ int wds[10];

  const int b = blockIdx.x;
  const int tid = threadIdx.x;

  if (tid < 10) wds[tid] = instr[(1+tid)*B_ + b];
  for (int i = tid; i < 550; i += 512) {
    int l = i / 11, j = i - l*11;
    SrT[j][l] = S_buf[(size_t)b*600 + l*12 + j];
  }
  for (int i = tid; i < 250; i += 512) ((float4*)iv)[i] = ((const float4*)iv_g)[i];
  __syncthreads();
  for (int wi = 0; wi < 10; ++wi) {
    const float4* __restrict__ src = (const float4*)(prim_emb + (size_t)wds[wi]*V_);
    for (int i = tid; i < 250; i += 512) ((float4*)prim[wi])[i] = src[i];
  }
  __syncthreads();

  const int wv = tid >> 6, lane = tid & 63;
  for (int l = wv; l < L_; l += 8) {
    float c0 = SrT[0][l];
    float cw[10];
    #pragma unroll
    for (int wi = 0; wi < 10; ++wi) cw[wi] = SrT[1+wi][l];
    float sv[16];
    float mx = -1e30f;
    #pragma unroll
    for (int jj = 0; jj < 16; ++jj) {
      int v = lane + 64*jj;
      float s = -1e30f;
      if (v < V_) {
        s = c0 * iv[v];
        #pragma unroll
        for (int wi = 0; wi < 10; ++wi) s += cw[wi]*prim[wi][v];
      }
      sv[jj] = s;
      mx = fmaxf(mx, s);
    }
    #pragma unroll
    for (int off = 32; off; off >>= 1) mx = fmaxf(mx, __shfl_xor(mx, off));
    float se = 0.f;
    #pragma unroll
    for (int jj = 0; jj < 16; ++jj) {
      int v = lane + 64*jj;
      if (v < V_) se += __expf(sv[jj] - mx);
    }
    #pragma unroll
    for (int off = 32; off; off >>= 1) se += __shfl_xor(se, off);
    if (lane == 0) lss[l] = mx + __logf(se);
  }
  __syncthreads();

  float* __restrict__ dst = out + (size_t)b*50000;
  for (int e = tid; e < 50000; e += 512) {
    const int v = e / 50, l = e - v*50;
    float s = SrT[0][l]*iv[v];
    #pragma unroll
    for (int wi = 0; wi < 10; ++wi) s += SrT[1+wi][l]*prim[wi][v];
    dst[e] = s - lss[l];
  }
}

// ---------------------------------------------------------------------------
extern "C" void kernel_launch(void* const* d_in, const int* in_sizes, int n_in,
                              void* d_out, int out_size, void* d_ws, size_t ws_size,
                              hipStream_t stream)
{
  (void)in_sizes; (void)n_in; (void)out_size; (void)ws_size;
  const float* gate_emb = (const float*)d_in[0];
  const float* prog_emb = (const float*)d_in[1];
  const float* prim_emb = (const float*)d_in[2];
  const float* sk       = (const float*)d_in[3];
  const float* iv       = (const float*)d_in[4];
  const float* w_ih     = (const float*)d_in[5];
  const float* w_hh     = (const float*)d_in[6];
  const float* b_ih     = (const float*)d_in[7];
  const float* b_hh     = (const float*)d_in[8];
  const int*   instr    = (const int*)d_in[9];
  const int*   tacts    = (const int*)d_in[10];
  float* out = (float*)d_out;

  float* ws     = (float*)d_ws;
  float* S_buf  = ws;                          // 256*600 f32
  float* g01    = S_buf + B_*600;              // 5120 f32
  float* giv    = g01 + NW_*B_*2;              // 1,152,000 f32
  unsigned char* whhP = (unsigned char*)(giv + (size_t)V_*H3_);  // 147456 B
  unsigned char* whhR = whhP + 147456;                           // 294912 B
  _Float16* wih_h  = (_Float16*)(whhR + 294912);             // 1152*224 f16
  _Float16* prog_h = wih_h + (size_t)H3_*224;                // 200000 f16
  _Float16* hdump  = prog_h + (size_t)V_*P_;                 // 31*16*384*16 f16

  hipLaunchKernelGGL(prep_kernel, dim3(1024), dim3(256), 0, stream,
      gate_emb, prog_emb, w_ih, w_hh, instr, tacts,
      g01, whhP, whhR, wih_h, prog_h, out);

  hipLaunchKernelGGL(gi_gemm, dim3(63, 18), dim3(256), 0, stream,
      prog_h, wih_h, b_ih, b_hh, giv);

  hipLaunchKernelGGL(steps_kernel, dim3(16), dim3(512), 0, stream,
      (const uint4*)whhP, (const uint4*)whhR, giv, g01, sk, b_hh, instr, hdump);

  hipLaunchKernelGGL(attnS_kernel, dim3(256), dim3(256), 0, stream,
      hdump, sk, g01, S_buf);

  hipLaunchKernelGGL(epi_kernel, dim3(256), dim3(512), 0, stream,
      S_buf, prim_emb, iv, instr, out);
}